// Round 8
// baseline (2136.958 us; speedup 1.0000x reference)
//
#include <hip/hip_runtime.h>
#include <hip/hip_fp16.h>

// Problem constants
#define B_   64
#define T_   512
#define I_   128
#define H_   256
#define G4_  1024   // 4*H
#define R_   20
#define DA_  50
#define C_   10

#define NA_  120    // W half2 per thread in AGPRs
#define NL_  8      // W half2 per thread in LDS

typedef _Float16 half2_t __attribute__((ext_vector_type(2)));
typedef _Float16 half8_t __attribute__((ext_vector_type(8)));

__device__ __forceinline__ float fsigmoid(float x) {
  return __fdividef(1.0f, 1.0f + __expf(-x));
}
__device__ __forceinline__ float ftanh(float x) {
  return 1.0f - __fdividef(2.0f, __expf(2.0f * x) + 1.0f);
}
__device__ __forceinline__ half2_t uh(unsigned x) {
  union { unsigned u; half2_t h; } c; c.u = x; return c.h;
}

// ---------------------------------------------------------------------------
// K0: pack W_hh [256][1024] fp32 -> Wq[g][k2] half2 (column-major per gate col)
// ---------------------------------------------------------------------------
__global__ __launch_bounds__(256) void k0_pack(const float* __restrict__ Whh,
                                               half2_t* __restrict__ Wq) {
  int idx = blockIdx.x * 256 + threadIdx.x;   // 0..131071
  int g = idx & 1023, k2 = idx >> 10;
  half2_t h;
  h.x = (_Float16)Whh[(2 * k2) * G4_ + g];
  h.y = (_Float16)Whh[(2 * k2 + 1) * G4_ + g];
  Wq[g * 128 + k2] = h;
}

// ---------------------------------------------------------------------------
// K0b: repack W for k5's per-thread AGPR/LDS layout.
// k5 thread t: uq = t>>4, kq = (t>>2)&3, g = t&3; covers cols
// col(colj) = g*256 + uq*4 + colj (colj 0..3) over k2 in [kq*32, kq*32+32).
// W element id e (0..127): e<112: i=e>>4, colj=(e>>2)&3, d=e&3 (k2=kq*32+i*4+d)
//   112..119: i=7, colj=(e-112)>>2, d=e&3  -> AGPR part WA[e][t]
//   120..127: i=7, colj=2+((e-120)>>2), d=e&3 -> LDS part WL[e-120][t]
// ---------------------------------------------------------------------------
__global__ __launch_bounds__(256) void k0b_pack(const half2_t* __restrict__ Wq,
                                                unsigned* __restrict__ WA,
                                                unsigned* __restrict__ WL) {
  int idx = blockIdx.x * 256 + threadIdx.x;   // 0..131071
  int t = idx & 1023, e = idx >> 10;          // e 0..127
  int uq = t >> 4, kq = (t >> 2) & 3, g = t & 3;
  int i, colj, d = e & 3;
  if (e < 112) {
    i = e >> 4; colj = (e >> 2) & 3;
  } else if (e < 120) {
    i = 7; colj = (e - 112) >> 2;
  } else {
    i = 7; colj = 2 + ((e - 120) >> 2);
  }
  int u = uq * 4 + colj;
  int col = g * 256 + u;
  int k2 = kq * 32 + i * 4 + d;
  union { half2_t h; unsigned v; } c;
  c.h = Wq[(size_t)col * 128 + k2];
  if (e < 120) WA[(size_t)e * 1024 + t] = c.v;
  else         WL[(size_t)(e - 120) * 1024 + t] = c.v;
}

// ---------------------------------------------------------------------------
// K1: S = (tanh(x@W1^T + b1))@W2^T + b2, layout S[B,R,T].
// ---------------------------------------------------------------------------
__global__ __launch_bounds__(256) void k1_scores(const float* __restrict__ x,
                                                 const float* __restrict__ W1,
                                                 const float* __restrict__ b1,
                                                 const float* __restrict__ W2,
                                                 const float* __restrict__ b2,
                                                 float* __restrict__ S) {
  __shared__ float xs[64][129];
  __shared__ float w1s[128][64];
  __shared__ float a1s[64][53];
  int blk = blockIdx.x;
  int tid = threadIdx.x;
  int row0 = blk * 64;
  const float4* xv = (const float4*)(x + (size_t)row0 * I_);
#pragma unroll
  for (int ch = 0; ch < 8; ch++) {
    int fidx = ch * 256 + tid;
    int r = fidx >> 5, k4 = (fidx & 31) << 2;
    float4 f = xv[fidx];
    xs[r][k4] = f.x; xs[r][k4 + 1] = f.y; xs[r][k4 + 2] = f.z; xs[r][k4 + 3] = f.w;
  }
  const float4* w1v = (const float4*)W1;
#pragma unroll
  for (int ch = 0; ch < 7; ch++) {
    int fidx = ch * 256 + tid;
    if (fidx < 1600) {
      int d = fidx >> 5, k4 = (fidx & 31) << 2;
      float4 f = w1v[fidx];
      w1s[k4][d] = f.x; w1s[k4 + 1][d] = f.y; w1s[k4 + 2][d] = f.z; w1s[k4 + 3][d] = f.w;
    }
  }
  __syncthreads();
  int ty = tid >> 4, tx = tid & 15;
  float acc[4][4] = {};
#pragma unroll 4
  for (int k = 0; k < I_; k++) {
    float a0 = xs[4 * ty][k], a1 = xs[4 * ty + 1][k];
    float a2 = xs[4 * ty + 2][k], a3 = xs[4 * ty + 3][k];
    float4 bq = *(const float4*)&w1s[k][tx << 2];
    acc[0][0] += a0 * bq.x; acc[0][1] += a0 * bq.y; acc[0][2] += a0 * bq.z; acc[0][3] += a0 * bq.w;
    acc[1][0] += a1 * bq.x; acc[1][1] += a1 * bq.y; acc[1][2] += a1 * bq.z; acc[1][3] += a1 * bq.w;
    acc[2][0] += a2 * bq.x; acc[2][1] += a2 * bq.y; acc[2][2] += a2 * bq.z; acc[2][3] += a2 * bq.w;
    acc[3][0] += a3 * bq.x; acc[3][1] += a3 * bq.y; acc[3][2] += a3 * bq.z; acc[3][3] += a3 * bq.w;
  }
#pragma unroll
  for (int i = 0; i < 4; i++) {
#pragma unroll
    for (int j = 0; j < 4; j++) {
      int col = (tx << 2) + j;
      if (col < DA_) a1s[4 * ty + i][col] = tanhf(acc[i][j] + b1[col]);
    }
  }
  __syncthreads();
  int row = tid & 63, rq = tid >> 6;
  int bt = row0 + row;
  int b = bt >> 9, t = bt & 511;
#pragma unroll
  for (int m = 0; m < 5; m++) {
    int r = rq + (m << 2);
    float acc2 = b2[r];
#pragma unroll 10
    for (int d = 0; d < DA_; d++) acc2 += a1s[row][d] * W2[r * DA_ + d];
    S[((size_t)(b * R_ + r)) * T_ + t] = acc2;
  }
}

// ---------------------------------------------------------------------------
// K2: per (b,r): m = max_t S; E = exp(S-m); invd[t] = 1/cumsum(E)[t]
// ---------------------------------------------------------------------------
__global__ __launch_bounds__(64) void k2_prefix(const float* __restrict__ S,
                                                float* __restrict__ E,
                                                float* __restrict__ invd) {
  int br = blockIdx.x;
  int l = threadIdx.x;
  const float* Sr = S + (size_t)br * T_;
  float v[8];
  float m = -1e30f;
#pragma unroll
  for (int c = 0; c < 8; c++) {
    v[c] = Sr[c * 64 + l];
    m = fmaxf(m, v[c]);
  }
#pragma unroll
  for (int off = 32; off; off >>= 1) m = fmaxf(m, __shfl_xor(m, off));
  float carry = 0.f;
  for (int c = 0; c < 8; c++) {
    float e = expf(v[c] - m);
    float s = e;
#pragma unroll
    for (int off = 1; off < 64; off <<= 1) {
      float u = __shfl_up(s, off);
      if (l >= off) s += u;
    }
    E[(size_t)br * T_ + c * 64 + l] = e;
    invd[(size_t)br * T_ + c * 64 + l] = 1.f / (carry + s);
    carry += __shfl(s, 63);
  }
}

// ---------------------------------------------------------------------------
// K3a: per (b, chunk): P[b][c][r][i] = sum_{t in chunk} E[b,r,t] * x[b,t,i]
// ---------------------------------------------------------------------------
__global__ __launch_bounds__(128) void k3a(const float* __restrict__ x,
                                           const float* __restrict__ E,
                                           float* __restrict__ P) {
  int b = blockIdx.x >> 3, c = blockIdx.x & 7;
  int i = threadIdx.x;
  int t0 = c * 64;
  __shared__ float es[2][R_];
  float acc[R_];
#pragma unroll
  for (int r = 0; r < R_; r++) acc[r] = 0.f;
  float rE = 0.f;
  if (i < R_) rE = E[((size_t)(b * R_ + i)) * T_ + t0];
  const float* xb = x + (size_t)b * T_ * I_;
  float xv = xb[(size_t)t0 * I_ + i];
  int buf = 0;
  for (int tt = 0; tt < 64; tt++) {
    if (i < R_) es[buf][i] = rE;
    __syncthreads();
    if (tt + 1 < 64) {
      if (i < R_) rE = E[((size_t)(b * R_ + i)) * T_ + t0 + tt + 1];
    }
    float xcur = xv;
    if (tt + 1 < 64) xv = xb[(size_t)(t0 + tt + 1) * I_ + i];
#pragma unroll
    for (int r = 0; r < R_; r++) acc[r] += es[buf][r] * xcur;
    buf ^= 1;
  }
#pragma unroll
  for (int r = 0; r < R_; r++)
    P[(size_t)((b * 8 + c) * R_ + r) * I_ + i] = acc[r];
}

// ---------------------------------------------------------------------------
// K3b: exclusive prefix of P over chunks, per (b,r,i). In place.
// ---------------------------------------------------------------------------
__global__ __launch_bounds__(256) void k3b(float* __restrict__ P) {
  int gid = blockIdx.x * 256 + threadIdx.x;
  int i = gid & 127;
  int r = (gid >> 7) % R_;
  int b = gid / (R_ * I_);
  float s = 0.f;
#pragma unroll
  for (int c = 0; c < 8; c++) {
    size_t idx = (size_t)((b * 8 + c) * R_ + r) * I_ + i;
    float v = P[idx];
    P[idx] = s;
    s += v;
  }
}

// ---------------------------------------------------------------------------
// K3c: per (b, chunk): acc init from P prefix, then 64 steps producing M.
// ---------------------------------------------------------------------------
__global__ __launch_bounds__(128) void k3c(const float* __restrict__ x,
                                           const float* __restrict__ E,
                                           const float* __restrict__ invd,
                                           const float* __restrict__ P,
                                           float* __restrict__ M) {
  int b = blockIdx.x >> 3, c = blockIdx.x & 7;
  int i = threadIdx.x;
  int t0 = c * 64;
  __shared__ float es[2][R_], ds[2][R_];
  float acc[R_];
#pragma unroll
  for (int r = 0; r < R_; r++)
    acc[r] = P[(size_t)((b * 8 + c) * R_ + r) * I_ + i];
  float rE = 0.f, rD = 0.f;
  if (i < R_)
    rE = E[((size_t)(b * R_ + i)) * T_ + t0];
  else if (i < 2 * R_)
    rD = invd[((size_t)(b * R_ + (i - R_))) * T_ + t0];
  const float* xb = x + (size_t)b * T_ * I_;
  float xv = xb[(size_t)t0 * I_ + i];
  int buf = 0;
  for (int tt = 0; tt < 64; tt++) {
    if (i < R_) es[buf][i] = rE;
    else if (i < 2 * R_) ds[buf][i - R_] = rD;
    __syncthreads();
    if (tt + 1 < 64) {
      if (i < R_)
        rE = E[((size_t)(b * R_ + i)) * T_ + t0 + tt + 1];
      else if (i < 2 * R_)
        rD = invd[((size_t)(b * R_ + (i - R_))) * T_ + t0 + tt + 1];
    }
    float xcur = xv;
    if (tt + 1 < 64) xv = xb[(size_t)(t0 + tt + 1) * I_ + i];
    float s = 0.f;
#pragma unroll
    for (int r = 0; r < R_; r++) {
      acc[r] += es[buf][r] * xcur;
      s += acc[r] * ds[buf][r];
    }
    M[(size_t)b * T_ * I_ + (size_t)(t0 + tt) * I_ + i] = s * (1.0f / R_);
    buf ^= 1;
  }
}

// ---------------------------------------------------------------------------
// K4: gx[row][perm(col)] = M[row,:] @ W_ih[:,col] + b[col].  Output fp16.
// perm(col): u=col&255, g=col>>8 -> slot = (u>>2)*16 + g*4 + (u&3),
// matching k5's leader-lane uint2 loads.
// ---------------------------------------------------------------------------
__global__ __launch_bounds__(256) void k4_gemm(const float* __restrict__ Mm,
                                               const float* __restrict__ Wih,
                                               const float* __restrict__ bg,
                                               __half* __restrict__ gx) {
  __shared__ float As[I_][64];
  __shared__ float Bs[I_][64];
  int row0 = blockIdx.x * 64, col0 = blockIdx.y * 64;
  int tid = threadIdx.x;
#pragma unroll
  for (int ch = 0; ch < 8; ch++) {
    int fidx = ch * 256 + tid;
    int r = fidx >> 5;
    int kk = (fidx & 31) << 2;
    float4 f = ((const float4*)(Mm + (size_t)(row0 + r) * I_))[fidx & 31];
    As[kk + 0][r] = f.x;
    As[kk + 1][r] = f.y;
    As[kk + 2][r] = f.z;
    As[kk + 3][r] = f.w;
  }
#pragma unroll
  for (int ch = 0; ch < 8; ch++) {
    int fidx = ch * 256 + tid;
    int k = fidx >> 4;
    int c4 = (fidx & 15) << 2;
    float4 f = *((const float4*)(Wih + (size_t)k * G4_ + col0 + c4));
    *((float4*)&Bs[k][c4]) = f;
  }
  __syncthreads();
  int ty = tid >> 4, tx = tid & 15;
  float acc[4][4] = {};
#pragma unroll 4
  for (int k = 0; k < I_; k++) {
    float4 a = *((float4*)&As[k][ty << 2]);
    float4 bq = *((float4*)&Bs[k][tx << 2]);
    acc[0][0] += a.x * bq.x; acc[0][1] += a.x * bq.y; acc[0][2] += a.x * bq.z; acc[0][3] += a.x * bq.w;
    acc[1][0] += a.y * bq.x; acc[1][1] += a.y * bq.y; acc[1][2] += a.y * bq.z; acc[1][3] += a.y * bq.w;
    acc[2][0] += a.z * bq.x; acc[2][1] += a.z * bq.y; acc[2][2] += a.z * bq.z; acc[2][3] += a.z * bq.w;
    acc[3][0] += a.w * bq.x; acc[3][1] += a.w * bq.y; acc[3][2] += a.w * bq.z; acc[3][3] += a.w * bq.w;
  }
#pragma unroll
  for (int ii = 0; ii < 4; ii++) {
#pragma unroll
    for (int jj = 0; jj < 4; jj++) {
      int row = row0 + (ty << 2) + ii;
      int col = col0 + (tx << 2) + jj;
      int u = col & 255, g = col >> 8;
      int perm = ((u >> 2) << 4) + (g << 2) + (u & 3);
      gx[(size_t)row * G4_ + perm] = __float2half(acc[ii][jj] + bg[col]);
    }
  }
}

// ---------------------------------------------------------------------------
// K5: LSTM scan, ONE 1024-thread block per b.  W_hh lives in the AGPR file:
// 120 half2/thread forced into AGPRs via "+a" asm (bypasses the occupancy
// heuristic that spilled "+v" pins) + 8 half2/thread in LDS.  Zero per-step
// VMEM streaming (only 2 KB gx).  Thread map: uq=t>>4, kq=(t>>2)&3, g=t&3;
// thread covers cols g*256+uq*4+{0..3} over k2 [kq*32,kq*32+32).
// h in padded LDS quads (stride 36 dwords -> conflict-free kq groups),
// kq-reduction via shfl_xor(4,8); gate gather via 4 KB gsum + 2nd barrier.
// LDS padded to 83 KB to force 1 block/CU (4 waves/EU -> full reg budget).
// ---------------------------------------------------------------------------
__global__ __launch_bounds__(1024)
__attribute__((amdgpu_waves_per_eu(4, 4)))
void k5_lstm(const __half* __restrict__ gx, const unsigned* __restrict__ WA,
             const unsigned* __restrict__ WL, float* __restrict__ hT) {
  int b = blockIdx.x;
  int tid = threadIdx.x;
  int uq = tid >> 4, kq = (tid >> 2) & 3, g = tid & 3;

  __shared__ __align__(16) unsigned hsU[2][144];   // padded h quads (+4/quad)
  __shared__ unsigned wlds[NL_ * 1024];            // W LDS part, 32 KB
  __shared__ float gsum[1024];                     // per-col gate preacts
  __shared__ char pad_force_1block[45056];         // LDS pad -> 1 block/CU

  if (hT == nullptr) pad_force_1block[tid] = 1;    // opaque guard, never true

  // ---- W AGPR part: 120 half2, forced into accumulator registers ----
  unsigned wa[NA_];
#pragma unroll
  for (int j = 0; j < NA_; j++) wa[j] = WA[(size_t)j * 1024 + tid];
#pragma unroll
  for (int j = 0; j < NA_; j++) asm volatile("" : "+a"(wa[j]));

  // ---- W LDS part ----
#pragma unroll
  for (int j = 0; j < NL_; j++) wlds[j * 1024 + tid] = WL[(size_t)j * 1024 + tid];
  if (tid < 144) hsU[0][tid] = 0x3C003C00u;        // h0 = 1.0 (covers pads)
  __syncthreads();

  float cstate = 1.0f;                             // cell threads tid < 256
  const __half* gxp = gx + (size_t)b * T_ * G4_;
  int lslot = uq * 16 + g * 4;                     // leader uint2 gx slot

  for (int t = 0; t < T_; t++) {
    // gx prefetch for leaders (kq==0): 4 cols packed as uint2
    uint2 gxu = {0, 0};
    if (kq == 0) gxu = *(const uint2*)(gxp + (size_t)t * G4_ + lslot);

    const unsigned* hb = &hsU[t & 1][kq * 36];
    float a0 = 0.f, a1 = 0.f, a2 = 0.f, a3 = 0.f;

    // W LDS tail regs (i=7, colj 2..3)
    unsigned wlr[NL_];
#pragma unroll
    for (int j = 0; j < NL_; j++) wlr[j] = wlds[j * 1024 + tid];

#pragma unroll
    for (int i = 0; i < 7; i++) {
      half8_t hv = *(const half8_t*)(hb + i * 4);
      half2_t h0 = ((half2_t*)&hv)[0], h1 = ((half2_t*)&hv)[1];
      half2_t h2 = ((half2_t*)&hv)[2], h3 = ((half2_t*)&hv)[3];
      a0 = __builtin_amdgcn_fdot2(uh(wa[i * 16 + 0]),  h0, a0, false);
      a0 = __builtin_amdgcn_fdot2(uh(wa[i * 16 + 1]),  h1, a0, false);
      a0 = __builtin_amdgcn_fdot2(uh(wa[i * 16 + 2]),  h2, a0, false);
      a0 = __builtin_amdgcn_fdot2(uh(wa[i * 16 + 3]),  h3, a0, false);
      a1 = __builtin_amdgcn_fdot2(uh(wa[i * 16 + 4]),  h0, a1, false);
      a1 = __builtin_amdgcn_fdot2(uh(wa[i * 16 + 5]),  h1, a1, false);
      a1 = __builtin_amdgcn_fdot2(uh(wa[i * 16 + 6]),  h2, a1, false);
      a1 = __builtin_amdgcn_fdot2(uh(wa[i * 16 + 7]),  h3, a1, false);
      a2 = __builtin_amdgcn_fdot2(uh(wa[i * 16 + 8]),  h0, a2, false);
      a2 = __builtin_amdgcn_fdot2(uh(wa[i * 16 + 9]),  h1, a2, false);
      a2 = __builtin_amdgcn_fdot2(uh(wa[i * 16 + 10]), h2, a2, false);
      a2 = __builtin_amdgcn_fdot2(uh(wa[i * 16 + 11]), h3, a2, false);
      a3 = __builtin_amdgcn_fdot2(uh(wa[i * 16 + 12]), h0, a3, false);
      a3 = __builtin_amdgcn_fdot2(uh(wa[i * 16 + 13]), h1, a3, false);
      a3 = __builtin_amdgcn_fdot2(uh(wa[i * 16 + 14]), h2, a3, false);
      a3 = __builtin_amdgcn_fdot2(uh(wa[i * 16 + 15]), h3, a3, false);
    }
    {  // i == 7: colj 0..1 from AGPR, colj 2..3 from LDS regs
      half8_t hv = *(const half8_t*)(hb + 28);
      half2_t h0 = ((half2_t*)&hv)[0], h1 = ((half2_t*)&hv)[1];
      half2_t h2 = ((half2_t*)&hv)[2], h3 = ((half2_t*)&hv)[3];
      a0 = __builtin_amdgcn_fdot2(uh(wa[112]), h0, a0, false);
      a0 = __builtin_amdgcn_fdot2(uh(wa[113]), h1, a0, false);
      a0 = __builtin_amdgcn_fdot2(uh(wa[114]), h2, a0, false);
      a0 = __builtin_amdgcn_fdot2(uh(wa[115]), h3, a0, false);
      a1 = __builtin_amdgcn_fdot2(uh(wa[116]), h0, a1, false);
      a1 = __builtin_amdgcn_fdot2(uh(wa[117]), h1, a1, false);
      a1 = __builtin_amdgcn_fdot2(uh(wa[118]), h2, a1, false);
      a1 = __builtin_amdgcn_fdot2(uh(wa[119]), h3, a1, false);
      a2 = __builtin_amdgcn_fdot2(uh(wlr[0]), h0, a2, false);
      a2 = __builtin_amdgcn_fdot2(uh(wlr[1]), h1, a2, false);
      a2 = __builtin_amdgcn_fdot2(uh(wlr[2]), h2, a2, false);
      a2 = __builtin_amdgcn_fdot2(uh(wlr[3]), h3, a2, false);
      a3 = __builtin_amdgcn_fdot2(uh(wlr[4]), h0, a3, false);
      a3 = __builtin_amdgcn_fdot2(uh(wlr[5]), h1, a3, false);
      a3 = __builtin_amdgcn_fdot2(uh(wlr[6]), h2, a3, false);
      a3 = __builtin_amdgcn_fdot2(uh(wlr[7]), h3, a3, false);
    }

    // reduce over kq (lanes differ by 4 and 8 within the wave)
    a0 += __shfl_xor(a0, 4); a0 += __shfl_xor(a0, 8);
    a1 += __shfl_xor(a1, 4); a1 += __shfl_xor(a1, 8);
    a2 += __shfl_xor(a2, 4); a2 += __shfl_xor(a2, 8);
    a3 += __shfl_xor(a3, 4); a3 += __shfl_xor(a3, 8);

    if (kq == 0) {
      __half2 gl = *(__half2*)&gxu.x;   // cols colj 0,1
      __half2 gh = *(__half2*)&gxu.y;   // cols colj 2,3
      gsum[lslot + 0] = a0 + (float)gl.x;
      gsum[lslot + 1] = a1 + (float)gl.y;
      gsum[lslot + 2] = a2 + (float)gh.x;
      gsum[lslot + 3] = a3 + (float)gh.y;
    }
    __syncthreads();

    // cell update: threads 0..255, unit u = tid; gsum index u_q*16+g*4+colj
    // for col (g,u): uq=u>>2, colj=u&3 -> gsum[(u>>2)*16 + g*4 + (u&3)]
    if (tid < 256) {
      int u = tid;
      int base = ((u >> 2) << 4) + (u & 3);
      float vi = gsum[base + 0];
      float vf = gsum[base + 4];
      float vg = gsum[base + 8];
      float vo = gsum[base + 12];
      vi = fsigmoid(vi);
      vf = fsigmoid(vf);
      vg = ftanh(vg);
      vo = fsigmoid(vo);
      cstate = vf * cstate + vi * vg;
      float h = vo * ftanh(cstate);
      int j = u >> 1, hkq = u >> 6, off = j & 31;
      __half* hp = (__half*)&hsU[(t + 1) & 1][0];
      hp[(hkq * 36 + off) * 2 + (u & 1)] = __float2half(h);
      if (t == T_ - 1) hT[b * H_ + u] = h;
    }
    __syncthreads();
  }
}

// ---------------------------------------------------------------------------
// K6: logits = hT @ Wfc^T + bfc; softmax.  One wave per b.
// ---------------------------------------------------------------------------
__global__ __launch_bounds__(64) void k6_head(const float* __restrict__ hT,
                                              const float* __restrict__ Wfc,
                                              const float* __restrict__ bfc,
                                              float* __restrict__ out) {
  int b = blockIdx.x, l = threadIdx.x;
  const float* h = hT + b * H_;
  float p[C_];
#pragma unroll
  for (int c = 0; c < C_; c++) p[c] = 0.f;
#pragma unroll
  for (int q = 0; q < 4; q++) {
    float hv = h[q * 64 + l];
#pragma unroll
    for (int c = 0; c < C_; c++) p[c] += hv * Wfc[c * H_ + q * 64 + l];
  }
#pragma unroll
  for (int c = 0; c < C_; c++)
    for (int off = 32; off; off >>= 1) p[c] += __shfl_xor(p[c], off);
  if (l == 0) {
    float m = -1e30f, e[C_], sum = 0.f;
    for (int c = 0; c < C_; c++) { p[c] += bfc[c]; m = fmaxf(m, p[c]); }
    for (int c = 0; c < C_; c++) { e[c] = expf(p[c] - m); sum += e[c]; }
    for (int c = 0; c < C_; c++) out[b * C_ + c] = e[c] / sum;
  }
}

// ---------------------------------------------------------------------------
// Workspace layout (float offsets):
//   S     [B,R,T]        wsf + 0        (dead after k2; WA/WL alias it)
//   WA    [120][1024]u32 wsf + 0        (122880 dwords, by k0b post-k2)
//   WL    [8][1024]u32   wsf + 122880   (8192 dwords)
//   E     [B,R,T]        wsf + 655360
//   INVD  [B,R,T]        wsf + 1310720
//   M     [B,T,I]        wsf + 1966080
//   hT    [B,H]          wsf + 6160384
//   Wq    [1024][128]h2  wsf + 6176768  (131072 dwords)
//   gx    [B,T,4H] fp16  wsf + 6307840  (16777216 dwords)
//   P     [B][8][R][I]   aliases gx region (P dead before k4 writes gx)
// ---------------------------------------------------------------------------
extern "C" void kernel_launch(void* const* d_in, const int* in_sizes, int n_in,
                              void* d_out, int out_size, void* d_ws, size_t ws_size,
                              hipStream_t stream) {
  const float* x   = (const float*)d_in[0];
  const float* Wih = (const float*)d_in[1];
  const float* Whh = (const float*)d_in[2];
  const float* bg  = (const float*)d_in[3];
  const float* W1  = (const float*)d_in[4];
  const float* b1  = (const float*)d_in[5];
  const float* W2  = (const float*)d_in[6];
  const float* b2  = (const float*)d_in[7];
  const float* Wfc = (const float*)d_in[8];
  const float* bfc = (const float*)d_in[9];
  float* out = (float*)d_out;

  float* wsf = (float*)d_ws;
  float* S    = wsf;
  unsigned* WA = (unsigned*)wsf;              // aliases S (S dead after k2)
  unsigned* WL = (unsigned*)(wsf + 122880);
  float* E    = wsf + 655360;
  float* INVD = wsf + 1310720;
  float* Mm   = wsf + 1966080;
  float* hT   = wsf + 6160384;
  half2_t* Wq = (half2_t*)(wsf + 6176768);
  __half* gx  = (__half*)(wsf + 6307840);
  float* P    = wsf + 6307840;                // aliases gx region

  hipLaunchKernelGGL(k0_pack,   dim3(512),     dim3(256),  0, stream, Whh, Wq);
  hipLaunchKernelGGL(k1_scores, dim3(512),     dim3(256),  0, stream, x, W1, b1, W2, b2, S);
  hipLaunchKernelGGL(k2_prefix, dim3(B_ * R_), dim3(64),   0, stream, S, E, INVD);
  hipLaunchKernelGGL(k0b_pack,  dim3(512),     dim3(256),  0, stream, Wq, WA, WL);
  hipLaunchKernelGGL(k3a,       dim3(512),     dim3(128),  0, stream, x, E, P);
  hipLaunchKernelGGL(k3b,       dim3(640),     dim3(256),  0, stream, P);
  hipLaunchKernelGGL(k3c,       dim3(512),     dim3(128),  0, stream, x, E, INVD, P, Mm);
  hipLaunchKernelGGL(k4_gemm,   dim3(512, 16), dim3(256),  0, stream, Mm, Wih, bg, gx);
  hipLaunchKernelGGL(k5_lstm,   dim3(B_),      dim3(1024), 0, stream, gx, WA, WL, hT);
  hipLaunchKernelGGL(k6_head,   dim3(B_),      dim3(64),   0, stream, hT, Wfc, bfc, out);
}

// Round 9
// 1252.252 us; speedup vs baseline: 1.7065x; 1.7065x over previous
//
#include <hip/hip_runtime.h>
#include <hip/hip_fp16.h>

// Problem constants
#define B_   64
#define T_   512
#define I_   128
#define H_   256
#define G4_  1024   // 4*H
#define R_   20
#define DA_  50
#define C_   10

typedef _Float16 half2_t __attribute__((ext_vector_type(2)));
typedef _Float16 half8_t __attribute__((ext_vector_type(8)));

union U4H { uint4 q; half2_t h[4]; };

__device__ __forceinline__ float fsigmoid(float x) {
  return __fdividef(1.0f, 1.0f + __expf(-x));
}
__device__ __forceinline__ float ftanh(float x) {
  return 1.0f - __fdividef(2.0f, __expf(2.0f * x) + 1.0f);
}

// ---------------------------------------------------------------------------
// K0: pack W_hh [256][1024] fp32 -> Wq[g][k2] half2 (column-major per gate col)
// ---------------------------------------------------------------------------
__global__ __launch_bounds__(256) void k0_pack(const float* __restrict__ Whh,
                                               half2_t* __restrict__ Wq) {
  int idx = blockIdx.x * 256 + threadIdx.x;   // 0..131071
  int g = idx & 1023, k2 = idx >> 10;
  half2_t h;
  h.x = (_Float16)Whh[(2 * k2) * G4_ + g];
  h.y = (_Float16)Whh[(2 * k2 + 1) * G4_ + g];
  Wq[g * 128 + k2] = h;
}

// ---------------------------------------------------------------------------
// K0b: pack W for k5's 8-way split: WP8[p*4096 + i*256 + tid] (uint4) holds
// k2 = (tid&1)*64 + 4i .. +3 of column gcol = gate*256 + p*32 + uloc,
// where c = tid>>1, gate = c>>5, uloc = c&31.
// ---------------------------------------------------------------------------
__global__ __launch_bounds__(256) void k0b_pack(const half2_t* __restrict__ Wq,
                                                uint4* __restrict__ WP8) {
  int j = blockIdx.x * 256 + threadIdx.x;   // 0..32767
  int tid = j & 255, pi = j >> 8;           // pi = p*16 + i
  int p = pi >> 4, i = pi & 15;
  int c = tid >> 1, kh = tid & 1;
  int gate = c >> 5, uloc = c & 31;
  int gcol = gate * 256 + p * 32 + uloc;
  WP8[j] = *(const uint4*)(Wq + (size_t)gcol * 128 + kh * 64 + 4 * i);
}

// ---------------------------------------------------------------------------
// K_init: zero the h-exchange mailboxes (16384 u64)
// ---------------------------------------------------------------------------
__global__ __launch_bounds__(256) void k_init(unsigned long long* __restrict__ Hx) {
  int i = blockIdx.x * 256 + threadIdx.x;
  Hx[i] = 0ull;
}

// ---------------------------------------------------------------------------
// K1: S = (tanh(x@W1^T + b1))@W2^T + b2, layout S[B,R,T].
// ---------------------------------------------------------------------------
__global__ __launch_bounds__(256) void k1_scores(const float* __restrict__ x,
                                                 const float* __restrict__ W1,
                                                 const float* __restrict__ b1,
                                                 const float* __restrict__ W2,
                                                 const float* __restrict__ b2,
                                                 float* __restrict__ S) {
  __shared__ float xs[64][129];
  __shared__ float w1s[128][64];
  __shared__ float a1s[64][53];
  int blk = blockIdx.x;
  int tid = threadIdx.x;
  int row0 = blk * 64;
  const float4* xv = (const float4*)(x + (size_t)row0 * I_);
#pragma unroll
  for (int ch = 0; ch < 8; ch++) {
    int fidx = ch * 256 + tid;
    int r = fidx >> 5, k4 = (fidx & 31) << 2;
    float4 f = xv[fidx];
    xs[r][k4] = f.x; xs[r][k4 + 1] = f.y; xs[r][k4 + 2] = f.z; xs[r][k4 + 3] = f.w;
  }
  const float4* w1v = (const float4*)W1;
#pragma unroll
  for (int ch = 0; ch < 7; ch++) {
    int fidx = ch * 256 + tid;
    if (fidx < 1600) {
      int d = fidx >> 5, k4 = (fidx & 31) << 2;
      float4 f = w1v[fidx];
      w1s[k4][d] = f.x; w1s[k4 + 1][d] = f.y; w1s[k4 + 2][d] = f.z; w1s[k4 + 3][d] = f.w;
    }
  }
  __syncthreads();
  int ty = tid >> 4, tx = tid & 15;
  float acc[4][4] = {};
#pragma unroll 4
  for (int k = 0; k < I_; k++) {
    float a0 = xs[4 * ty][k], a1 = xs[4 * ty + 1][k];
    float a2 = xs[4 * ty + 2][k], a3 = xs[4 * ty + 3][k];
    float4 bq = *(const float4*)&w1s[k][tx << 2];
    acc[0][0] += a0 * bq.x; acc[0][1] += a0 * bq.y; acc[0][2] += a0 * bq.z; acc[0][3] += a0 * bq.w;
    acc[1][0] += a1 * bq.x; acc[1][1] += a1 * bq.y; acc[1][2] += a1 * bq.z; acc[1][3] += a1 * bq.w;
    acc[2][0] += a2 * bq.x; acc[2][1] += a2 * bq.y; acc[2][2] += a2 * bq.z; acc[2][3] += a2 * bq.w;
    acc[3][0] += a3 * bq.x; acc[3][1] += a3 * bq.y; acc[3][2] += a3 * bq.z; acc[3][3] += a3 * bq.w;
  }
#pragma unroll
  for (int i = 0; i < 4; i++) {
#pragma unroll
    for (int j = 0; j < 4; j++) {
      int col = (tx << 2) + j;
      if (col < DA_) a1s[4 * ty + i][col] = tanhf(acc[i][j] + b1[col]);
    }
  }
  __syncthreads();
  int row = tid & 63, rq = tid >> 6;
  int bt = row0 + row;
  int b = bt >> 9, t = bt & 511;
#pragma unroll
  for (int m = 0; m < 5; m++) {
    int r = rq + (m << 2);
    float acc2 = b2[r];
#pragma unroll 10
    for (int d = 0; d < DA_; d++) acc2 += a1s[row][d] * W2[r * DA_ + d];
    S[((size_t)(b * R_ + r)) * T_ + t] = acc2;
  }
}

// ---------------------------------------------------------------------------
// K2: per (b,r): m = max_t S; E = exp(S-m); invd[t] = 1/cumsum(E)[t]
// ---------------------------------------------------------------------------
__global__ __launch_bounds__(64) void k2_prefix(const float* __restrict__ S,
                                                float* __restrict__ E,
                                                float* __restrict__ invd) {
  int br = blockIdx.x;
  int l = threadIdx.x;
  const float* Sr = S + (size_t)br * T_;
  float v[8];
  float m = -1e30f;
#pragma unroll
  for (int c = 0; c < 8; c++) {
    v[c] = Sr[c * 64 + l];
    m = fmaxf(m, v[c]);
  }
#pragma unroll
  for (int off = 32; off; off >>= 1) m = fmaxf(m, __shfl_xor(m, off));
  float carry = 0.f;
  for (int c = 0; c < 8; c++) {
    float e = expf(v[c] - m);
    float s = e;
#pragma unroll
    for (int off = 1; off < 64; off <<= 1) {
      float u = __shfl_up(s, off);
      if (l >= off) s += u;
    }
    E[(size_t)br * T_ + c * 64 + l] = e;
    invd[(size_t)br * T_ + c * 64 + l] = 1.f / (carry + s);
    carry += __shfl(s, 63);
  }
}

// ---------------------------------------------------------------------------
// K3a: per (b, chunk): P[b][c][r][i] = sum_{t in chunk} E[b,r,t] * x[b,t,i]
// ---------------------------------------------------------------------------
__global__ __launch_bounds__(128) void k3a(const float* __restrict__ x,
                                           const float* __restrict__ E,
                                           float* __restrict__ P) {
  int b = blockIdx.x >> 3, c = blockIdx.x & 7;
  int i = threadIdx.x;
  int t0 = c * 64;
  __shared__ float es[2][R_];
  float acc[R_];
#pragma unroll
  for (int r = 0; r < R_; r++) acc[r] = 0.f;
  float rE = 0.f;
  if (i < R_) rE = E[((size_t)(b * R_ + i)) * T_ + t0];
  const float* xb = x + (size_t)b * T_ * I_;
  float xv = xb[(size_t)t0 * I_ + i];
  int buf = 0;
  for (int tt = 0; tt < 64; tt++) {
    if (i < R_) es[buf][i] = rE;
    __syncthreads();
    if (tt + 1 < 64) {
      if (i < R_) rE = E[((size_t)(b * R_ + i)) * T_ + t0 + tt + 1];
    }
    float xcur = xv;
    if (tt + 1 < 64) xv = xb[(size_t)(t0 + tt + 1) * I_ + i];
#pragma unroll
    for (int r = 0; r < R_; r++) acc[r] += es[buf][r] * xcur;
    buf ^= 1;
  }
#pragma unroll
  for (int r = 0; r < R_; r++)
    P[(size_t)((b * 8 + c) * R_ + r) * I_ + i] = acc[r];
}

// ---------------------------------------------------------------------------
// K3b: exclusive prefix of P over chunks, per (b,r,i). In place.
// ---------------------------------------------------------------------------
__global__ __launch_bounds__(256) void k3b(float* __restrict__ P) {
  int gid = blockIdx.x * 256 + threadIdx.x;
  int i = gid & 127;
  int r = (gid >> 7) % R_;
  int b = gid / (R_ * I_);
  float s = 0.f;
#pragma unroll
  for (int c = 0; c < 8; c++) {
    size_t idx = (size_t)((b * 8 + c) * R_ + r) * I_ + i;
    float v = P[idx];
    P[idx] = s;
    s += v;
  }
}

// ---------------------------------------------------------------------------
// K3c: per (b, chunk): acc init from P prefix, then 64 steps producing M.
// ---------------------------------------------------------------------------
__global__ __launch_bounds__(128) void k3c(const float* __restrict__ x,
                                           const float* __restrict__ E,
                                           const float* __restrict__ invd,
                                           const float* __restrict__ P,
                                           float* __restrict__ M) {
  int b = blockIdx.x >> 3, c = blockIdx.x & 7;
  int i = threadIdx.x;
  int t0 = c * 64;
  __shared__ float es[2][R_], ds[2][R_];
  float acc[R_];
#pragma unroll
  for (int r = 0; r < R_; r++)
    acc[r] = P[(size_t)((b * 8 + c) * R_ + r) * I_ + i];
  float rE = 0.f, rD = 0.f;
  if (i < R_)
    rE = E[((size_t)(b * R_ + i)) * T_ + t0];
  else if (i < 2 * R_)
    rD = invd[((size_t)(b * R_ + (i - R_))) * T_ + t0];
  const float* xb = x + (size_t)b * T_ * I_;
  float xv = xb[(size_t)t0 * I_ + i];
  int buf = 0;
  for (int tt = 0; tt < 64; tt++) {
    if (i < R_) es[buf][i] = rE;
    else if (i < 2 * R_) ds[buf][i - R_] = rD;
    __syncthreads();
    if (tt + 1 < 64) {
      if (i < R_)
        rE = E[((size_t)(b * R_ + i)) * T_ + t0 + tt + 1];
      else if (i < 2 * R_)
        rD = invd[((size_t)(b * R_ + (i - R_))) * T_ + t0 + tt + 1];
    }
    float xcur = xv;
    if (tt + 1 < 64) xv = xb[(size_t)(t0 + tt + 1) * I_ + i];
    float s = 0.f;
#pragma unroll
    for (int r = 0; r < R_; r++) {
      acc[r] += es[buf][r] * xcur;
      s += acc[r] * ds[buf][r];
    }
    M[(size_t)b * T_ * I_ + (size_t)(t0 + tt) * I_ + i] = s * (1.0f / R_);
    buf ^= 1;
  }
}

// ---------------------------------------------------------------------------
// K4: gx[row][perm(col)] = M[row,:] @ W_ih[:,col] + b[col].  Output fp16.
// perm(col): u = col&255, g = col>>8 -> slot = u*4 + g  (unit-major), so
// k5 block p reads a contiguous 256 B slice [p*128, p*128+128).
// ---------------------------------------------------------------------------
__global__ __launch_bounds__(256) void k4_gemm(const float* __restrict__ Mm,
                                               const float* __restrict__ Wih,
                                               const float* __restrict__ bg,
                                               __half* __restrict__ gx) {
  __shared__ float As[I_][64];
  __shared__ float Bs[I_][64];
  int row0 = blockIdx.x * 64, col0 = blockIdx.y * 64;
  int tid = threadIdx.x;
#pragma unroll
  for (int ch = 0; ch < 8; ch++) {
    int fidx = ch * 256 + tid;
    int r = fidx >> 5;
    int kk = (fidx & 31) << 2;
    float4 f = ((const float4*)(Mm + (size_t)(row0 + r) * I_))[fidx & 31];
    As[kk + 0][r] = f.x;
    As[kk + 1][r] = f.y;
    As[kk + 2][r] = f.z;
    As[kk + 3][r] = f.w;
  }
#pragma unroll
  for (int ch = 0; ch < 8; ch++) {
    int fidx = ch * 256 + tid;
    int k = fidx >> 4;
    int c4 = (fidx & 15) << 2;
    float4 f = *((const float4*)(Wih + (size_t)k * G4_ + col0 + c4));
    *((float4*)&Bs[k][c4]) = f;
  }
  __syncthreads();
  int ty = tid >> 4, tx = tid & 15;
  float acc[4][4] = {};
#pragma unroll 4
  for (int k = 0; k < I_; k++) {
    float4 a = *((float4*)&As[k][ty << 2]);
    float4 bq = *((float4*)&Bs[k][tx << 2]);
    acc[0][0] += a.x * bq.x; acc[0][1] += a.x * bq.y; acc[0][2] += a.x * bq.z; acc[0][3] += a.x * bq.w;
    acc[1][0] += a.y * bq.x; acc[1][1] += a.y * bq.y; acc[1][2] += a.y * bq.z; acc[1][3] += a.y * bq.w;
    acc[2][0] += a.z * bq.x; acc[2][1] += a.z * bq.y; acc[2][2] += a.z * bq.z; acc[2][3] += a.z * bq.w;
    acc[3][0] += a.w * bq.x; acc[3][1] += a.w * bq.y; acc[3][2] += a.w * bq.z; acc[3][3] += a.w * bq.w;
  }
#pragma unroll
  for (int ii = 0; ii < 4; ii++) {
#pragma unroll
    for (int jj = 0; jj < 4; jj++) {
      int row = row0 + (ty << 2) + ii;
      int col = col0 + (tx << 2) + jj;
      int u = col & 255, g = col >> 8;
      int perm = (u << 2) | g;
      gx[(size_t)row * G4_ + perm] = __float2half(acc[ii][jj] + bg[col]);
    }
  }
}

// ---------------------------------------------------------------------------
// K5: LSTM scan, 8 blocks per b (512 blocks x 256 thr, 2 blocks/CU, all
// co-resident). Block (p, b): units [p*32, p*32+32), ALL 4 gates -> cell
// update is block-local. W slice (64 KB) lives in LDS — no register games.
// Per step: W-regs prefetched from LDS BEFORE the mailbox poll (overlap);
// h exchange via R3-proven tagged 8B packets (relaxed agent atomics, parity
// double-buffer, lap-safe). Thread: c = tid>>1 (col), kh = tid&1 (k-half).
// ---------------------------------------------------------------------------
__global__ __launch_bounds__(256, 2) void k5_lstm(
    const __half* __restrict__ gx, const uint4* __restrict__ WP8,
    unsigned long long* __restrict__ Hx, float* __restrict__ hT) {
  int blk = blockIdx.x;
  int b = blk & 63, p = blk >> 6;
  int tid = threadIdx.x;
  int c = tid >> 1, kh = tid & 1;

  __shared__ __align__(16) uint4 wlds[16 * 256];   // W slice, 64 KB
  __shared__ __align__(16) unsigned hsU[2][128];   // h fp16 double-buffer
  __shared__ float gsum[128];

  // one-time W LDS fill
  {
    const uint4* wp = WP8 + (size_t)p * 4096;
#pragma unroll
    for (int i = 0; i < 16; i++) wlds[i * 256 + tid] = wp[i * 256 + tid];
  }
  if (tid < 128) hsU[0][tid] = 0x3C003C00u;        // h0 = 1.0 pairs
  __syncthreads();

  float cstate = 1.0f;                             // cell threads tid < 32
  const __half* gxp = gx + (size_t)b * T_ * G4_ + p * 128;
  int gxi = ((c & 31) << 2) | (c >> 5);            // in-slice gx index
  int s = (tid < p * 16) ? tid : tid + 16;         // poll slot (tid < 112)

  for (int t = 0; t < T_; t++) {
    // prefetch W into regs (LDS, fast) and gx (VMEM) — both overlap the poll
    uint4 w[16];
#pragma unroll
    for (int i = 0; i < 16; i++) w[i] = wlds[i * 256 + tid];
    float gxv = 0.f;
    if (!kh) gxv = (float)gxp[(size_t)t * G4_ + gxi];

    // stage h(t): remote slices via mailbox (own slice written locally at t-1)
    if (t > 0 && tid < 112) {
      const unsigned long long* src =
          Hx + ((size_t)(t & 1) * 64 + b) * 128 + s;
      unsigned long long v;
      do {
        v = __hip_atomic_load(src, __ATOMIC_RELAXED, __HIP_MEMORY_SCOPE_AGENT);
      } while ((unsigned)(v >> 32) != (unsigned)t);
      hsU[t & 1][s] = (unsigned)v;
    }
    __syncthreads();

    // dot over k-half kh: 64 half2, W in regs, h broadcast from LDS
    const half2_t* hb = (const half2_t*)hsU[t & 1] + kh * 64;
    float a0 = 0.f, a1 = 0.f, a2 = 0.f, a3 = 0.f;
#pragma unroll
    for (int i = 0; i < 16; i++) {
      U4H wc; wc.q = w[i];
      half8_t hv = *(const half8_t*)(hb + i * 4);
      a0 = __builtin_amdgcn_fdot2(wc.h[0], ((half2_t*)&hv)[0], a0, false);
      a1 = __builtin_amdgcn_fdot2(wc.h[1], ((half2_t*)&hv)[1], a1, false);
      a2 = __builtin_amdgcn_fdot2(wc.h[2], ((half2_t*)&hv)[2], a2, false);
      a3 = __builtin_amdgcn_fdot2(wc.h[3], ((half2_t*)&hv)[3], a3, false);
    }
    float sv = (a0 + a1) + (a2 + a3);
    sv += __shfl_xor(sv, 1);                       // combine k-halves
    if (!kh) gsum[c] = sv + gxv;
    __syncthreads();

    // cell update: tid < 32 owns unit p*32 + tid (cols gate*32 + tid in gsum)
    if (tid < 32) {
      float vi = gsum[tid], vf = gsum[32 + tid], vg = gsum[64 + tid],
            vo = gsum[96 + tid];
      vi = fsigmoid(vi);
      vf = fsigmoid(vf);
      vg = ftanh(vg);
      vo = fsigmoid(vo);
      cstate = vf * cstate + vi * vg;
      float h = vo * ftanh(cstate);
      unsigned hu = (unsigned)__half_as_ushort(__float2half(h));
      unsigned hup = (unsigned)__shfl_down((int)hu, 1);
      if (!(tid & 1)) {
        unsigned pair = hu | (hup << 16);
        int slot = p * 16 + (tid >> 1);
        hsU[(t + 1) & 1][slot] = pair;             // own slice, local
        if (t + 1 < T_) {
          unsigned long long pkt =
              (unsigned long long)pair |
              ((unsigned long long)(unsigned)(t + 1) << 32);
          __hip_atomic_store(
              Hx + ((size_t)((t + 1) & 1) * 64 + b) * 128 + slot, pkt,
              __ATOMIC_RELAXED, __HIP_MEMORY_SCOPE_AGENT);
        }
      }
      if (t == T_ - 1) hT[b * H_ + p * 32 + tid] = h;
    }
    // no third barrier: next-step pollers write disjoint (remote) hsU slots,
    // and the t+1 stage-barrier orders cell writes before all dot reads.
  }
}

// ---------------------------------------------------------------------------
// K6: logits = hT @ Wfc^T + bfc; softmax.  One wave per b.
// ---------------------------------------------------------------------------
__global__ __launch_bounds__(64) void k6_head(const float* __restrict__ hT,
                                              const float* __restrict__ Wfc,
                                              const float* __restrict__ bfc,
                                              float* __restrict__ out) {
  int b = blockIdx.x, l = threadIdx.x;
  const float* h = hT + b * H_;
  float p[C_];
#pragma unroll
  for (int c = 0; c < C_; c++) p[c] = 0.f;
#pragma unroll
  for (int q = 0; q < 4; q++) {
    float hv = h[q * 64 + l];
#pragma unroll
    for (int c = 0; c < C_; c++) p[c] += hv * Wfc[c * H_ + q * 64 + l];
  }
#pragma unroll
  for (int c = 0; c < C_; c++)
    for (int off = 32; off; off >>= 1) p[c] += __shfl_xor(p[c], off);
  if (l == 0) {
    float m = -1e30f, e[C_], sum = 0.f;
    for (int c = 0; c < C_; c++) { p[c] += bfc[c]; m = fmaxf(m, p[c]); }
    for (int c = 0; c < C_; c++) { e[c] = expf(p[c] - m); sum += e[c]; }
    for (int c = 0; c < C_; c++) out[b * C_ + c] = e[c] / sum;
  }
}

// ---------------------------------------------------------------------------
// Workspace layout (float offsets):
//   S     [B,R,T]        wsf + 0        (dead after k2; WP8/Hx alias it)
//   WP8   [8][16][256]u4 wsf + 0        (131072 dwords; k0b writes post-k2)
//   Hx    [2][64][128]u64 wsf + 131072  (32768 dwords; k_init zeroes)
//   E     [B,R,T]        wsf + 655360
//   INVD  [B,R,T]        wsf + 1310720
//   M     [B,T,I]        wsf + 1966080
//   hT    [B,H]          wsf + 6160384
//   Wq    [1024][128]h2  wsf + 6176768  (131072 dwords)
//   gx    [B,T,4H] fp16  wsf + 6307840  (16777216 dwords)
//   P     [B][8][R][I]   aliases gx region (P dead before k4 writes gx)
// ---------------------------------------------------------------------------
extern "C" void kernel_launch(void* const* d_in, const int* in_sizes, int n_in,
                              void* d_out, int out_size, void* d_ws, size_t ws_size,
                              hipStream_t stream) {
  const float* x   = (const float*)d_in[0];
  const float* Wih = (const float*)d_in[1];
  const float* Whh = (const float*)d_in[2];
  const float* bg  = (const float*)d_in[3];
  const float* W1  = (const float*)d_in[4];
  const float* b1  = (const float*)d_in[5];
  const float* W2  = (const float*)d_in[6];
  const float* b2  = (const float*)d_in[7];
  const float* Wfc = (const float*)d_in[8];
  const float* bfc = (const float*)d_in[9];
  float* out = (float*)d_out;

  float* wsf = (float*)d_ws;
  float* S    = wsf;
  uint4* WP8  = (uint4*)wsf;                       // aliases S (dead post-k2)
  unsigned long long* Hx = (unsigned long long*)(wsf + 131072);
  float* E    = wsf + 655360;
  float* INVD = wsf + 1310720;
  float* Mm   = wsf + 1966080;
  float* hT   = wsf + 6160384;
  half2_t* Wq = (half2_t*)(wsf + 6176768);
  __half* gx  = (__half*)(wsf + 6307840);
  float* P    = wsf + 6307840;                     // aliases gx region

  hipLaunchKernelGGL(k0_pack,   dim3(512),     dim3(256), 0, stream, Whh, Wq);
  hipLaunchKernelGGL(k1_scores, dim3(512),     dim3(256), 0, stream, x, W1, b1, W2, b2, S);
  hipLaunchKernelGGL(k2_prefix, dim3(B_ * R_), dim3(64),  0, stream, S, E, INVD);
  hipLaunchKernelGGL(k0b_pack,  dim3(128),     dim3(256), 0, stream, Wq, WP8);
  hipLaunchKernelGGL(k_init,    dim3(64),      dim3(256), 0, stream, Hx);
  hipLaunchKernelGGL(k3a,       dim3(512),     dim3(128), 0, stream, x, E, P);
  hipLaunchKernelGGL(k3b,       dim3(640),     dim3(256), 0, stream, P);
  hipLaunchKernelGGL(k3c,       dim3(512),     dim3(128), 0, stream, x, E, INVD, P, Mm);
  hipLaunchKernelGGL(k4_gemm,   dim3(512, 16), dim3(256), 0, stream, Mm, Wih, bg, gx);
  hipLaunchKernelGGL(k5_lstm,   dim3(512),     dim3(256), 0, stream, gx, WP8, Hx, hT);
  hipLaunchKernelGGL(k6_head,   dim3(B_),      dim3(64),  0, stream, hT, Wfc, bfc, out);
}